// Round 1
// baseline (65.751 us; speedup 1.0000x reference)
//
#include <hip/hip_runtime.h>
#include <math.h>

#define BATCH 512
#define SEQL  2048
#define NPTS  (SEQL*3)        // 6144 points per batch
#define NFLT  (NPTS*3)        // 18432 floats per batch per tensor
#define NGRP  (NPTS/4)        // 1536 groups of 4 points

// ---------------- mask dtype handling ----------------
// flag: 0 = int32 {0,1}, 1 = uint8 {0,1}, 2 = float32 {0,1}
__device__ __forceinline__ float load_mask(const void* m, int flag, size_t idx) {
    if (flag == 0) return ((const int*)m)[idx] != 0 ? 1.0f : 0.0f;
    if (flag == 1) return ((const unsigned char*)m)[idx] != 0 ? 1.0f : 0.0f;
    return ((const float*)m)[idx] != 0.0f ? 1.0f : 0.0f;
}

__global__ void k_detect(const unsigned int* __restrict__ words, int nwords,
                         int* __restrict__ flag) {
    if (blockIdx.x == 0 && threadIdx.x == 0) {
        bool all_int = true, all_byte = true;
        for (int i = 0; i < nwords; ++i) {
            unsigned int v = words[i];
            if (v > 1u) all_int = false;
            if ((v & 0xFEFEFEFEu) != 0u) all_byte = false;
        }
        *flag = all_int ? 0 : (all_byte ? 1 : 2);
    }
}

// ---------------- reduction helpers ----------------
template <int K>
__device__ __forceinline__ void block_reduce(float* acc, float* lds) {
#pragma unroll
    for (int k = 0; k < K; ++k) {
#pragma unroll
        for (int off = 32; off > 0; off >>= 1)
            acc[k] += __shfl_down(acc[k], off, 64);
    }
    int lane = threadIdx.x & 63;
    int wid  = threadIdx.x >> 6;
    if (lane == 0) {
#pragma unroll
        for (int k = 0; k < K; ++k) lds[wid * K + k] = acc[k];
    }
    __syncthreads();
    if (threadIdx.x == 0) {
#pragma unroll
        for (int k = 0; k < K; ++k)
            acc[k] = lds[0 * K + k] + lds[1 * K + k] + lds[2 * K + k] + lds[3 * K + k];
    }
}

__device__ __forceinline__ void accum_pt(float* a, float w,
                                         float px, float py, float pz,
                                         float qx, float qy, float qz) {
    a[0] += w;
    float wpx = w * px, wpy = w * py, wpz = w * pz;
    a[1] += wpx; a[2] += wpy; a[3] += wpz;
    a[4] += w * qx; a[5] += w * qy; a[6] += w * qz;
    a[7]  += wpx * qx; a[8]  += wpx * qy; a[9]  += wpx * qz;
    a[10] += wpy * qx; a[11] += wpy * qy; a[12] += wpy * qz;
    a[13] += wpz * qx; a[14] += wpz * qy; a[15] += wpz * qz;
}

// ---------------- pass 1: per-batch sums ----------------
// out per batch (stride 32): [0]=cnt [1..3]=sum wP [4..6]=sum wQ
// [7..15]=sum w*P_i*Q_j (row-major i,j) [16]=residue count
__global__ __launch_bounds__(256) void k_sums(
    const float* __restrict__ P, const float* __restrict__ Q,
    const void* __restrict__ cmask, const void* __restrict__ rmask,
    const int* __restrict__ flagp, float* __restrict__ sums) {
    int b = blockIdx.x;
    int flag = *flagp;
    const float4* Pv = (const float4*)(P + (size_t)b * NFLT);
    const float4* Qv = (const float4*)(Q + (size_t)b * NFLT);
    size_t mbase = (size_t)b * NPTS;

    float acc[17];
#pragma unroll
    for (int k = 0; k < 17; ++k) acc[k] = 0.0f;

    for (int g = threadIdx.x; g < NGRP; g += 256) {
        float4 p0 = Pv[3 * g + 0], p1 = Pv[3 * g + 1], p2 = Pv[3 * g + 2];
        float4 q0 = Qv[3 * g + 0], q1 = Qv[3 * g + 1], q2 = Qv[3 * g + 2];
        float w0 = load_mask(cmask, flag, mbase + 4 * g + 0);
        float w1 = load_mask(cmask, flag, mbase + 4 * g + 1);
        float w2 = load_mask(cmask, flag, mbase + 4 * g + 2);
        float w3 = load_mask(cmask, flag, mbase + 4 * g + 3);
        accum_pt(acc, w0, p0.x, p0.y, p0.z, q0.x, q0.y, q0.z);
        accum_pt(acc, w1, p0.w, p1.x, p1.y, q0.w, q1.x, q1.y);
        accum_pt(acc, w2, p1.z, p1.w, p2.x, q1.z, q1.w, q2.x);
        accum_pt(acc, w3, p2.y, p2.z, p2.w, q2.y, q2.z, q2.w);
    }
    for (int i = threadIdx.x; i < SEQL; i += 256)
        acc[16] += load_mask(rmask, flag, (size_t)b * SEQL + i);

    __shared__ float lds[4 * 17];
    block_reduce<17>(acc, lds);
    if (threadIdx.x == 0) {
#pragma unroll
        for (int k = 0; k < 17; ++k) sums[b * 32 + k] = acc[k];
    }
}

// ---------------- pass 2: per-batch 3x3 Kabsch (double precision) ----------------
// params per batch (stride 32): [0..8]=R row-major, [9..11]=muP, [12..14]=muQ,
// [15]=1/d0^2, [16]=cnt
__device__ __forceinline__ void normalize3(double* v) {
    double n = sqrt(v[0] * v[0] + v[1] * v[1] + v[2] * v[2]);
    if (n > 1e-300) { v[0] /= n; v[1] /= n; v[2] /= n; }
}
__device__ __forceinline__ void cross3(const double* a, const double* b, double* c) {
    c[0] = a[1] * b[2] - a[2] * b[1];
    c[1] = a[2] * b[0] - a[0] * b[2];
    c[2] = a[0] * b[1] - a[1] * b[0];
}

__global__ void k_svd(const float* __restrict__ sums, float* __restrict__ params) {
    int b = blockIdx.x * blockDim.x + threadIdx.x;
    if (b >= BATCH) return;
    const float* s = sums + b * 32;
    double cnt = (double)s[0];
    double cs = fmax(cnt, 1.0);
    double mup[3], muq[3];
#pragma unroll
    for (int i = 0; i < 3; ++i) { mup[i] = (double)s[1 + i] / cs; muq[i] = (double)s[4 + i] / cs; }
    double Hm[3][3];
#pragma unroll
    for (int i = 0; i < 3; ++i)
#pragma unroll
        for (int j = 0; j < 3; ++j)
            Hm[i][j] = (double)s[7 + 3 * i + j] - cnt * mup[i] * muq[j];

    // A = H^T H (symmetric PSD)
    double A[3][3];
#pragma unroll
    for (int i = 0; i < 3; ++i)
#pragma unroll
        for (int j = 0; j < 3; ++j)
            A[i][j] = Hm[0][i] * Hm[0][j] + Hm[1][i] * Hm[1][j] + Hm[2][i] * Hm[2][j];

    double V[3][3] = {{1, 0, 0}, {0, 1, 0}, {0, 0, 1}};
    const int PP[3] = {0, 0, 1}, QQ[3] = {1, 2, 2};
    for (int sweep = 0; sweep < 10; ++sweep) {
        for (int r = 0; r < 3; ++r) {
            int p = PP[r], q = QQ[r];
            double apq = A[p][q];
            if (fabs(apq) < 1e-280) continue;
            double tau = (A[q][q] - A[p][p]) / (2.0 * apq);
            double t = (tau >= 0.0 ? 1.0 : -1.0) / (fabs(tau) + sqrt(1.0 + tau * tau));
            double c = 1.0 / sqrt(1.0 + t * t);
            double sn = t * c;
            for (int k = 0; k < 3; ++k) {  // A <- A*J
                double akp = A[k][p], akq = A[k][q];
                A[k][p] = c * akp - sn * akq;
                A[k][q] = sn * akp + c * akq;
            }
            for (int k = 0; k < 3; ++k) {  // A <- J^T*A
                double apk = A[p][k], aqk = A[q][k];
                A[p][k] = c * apk - sn * aqk;
                A[q][k] = sn * apk + c * aqk;
            }
            for (int k = 0; k < 3; ++k) {  // V <- V*J
                double vkp = V[k][p], vkq = V[k][q];
                V[k][p] = c * vkp - sn * vkq;
                V[k][q] = sn * vkp + c * vkq;
            }
        }
    }
    double lam[3] = {A[0][0], A[1][1], A[2][2]};
    int idx[3] = {0, 1, 2};
#pragma unroll
    for (int i = 0; i < 2; ++i)
#pragma unroll
        for (int j = 0; j < 2 - i; ++j)
            if (lam[idx[j]] < lam[idx[j + 1]]) { int t = idx[j]; idx[j] = idx[j + 1]; idx[j + 1] = t; }

    double Vs[3][3];  // sorted right singular vectors (columns)
#pragma unroll
    for (int k = 0; k < 3; ++k)
        for (int i = 0; i < 3; ++i) Vs[i][k] = V[i][idx[k]];
    double sv[3];
#pragma unroll
    for (int k = 0; k < 3; ++k) sv[k] = sqrt(fmax(lam[idx[k]], 0.0));

    // U columns: u_k = H v_k / s_k, with degeneracy guards
    double U[3][3];
    double eps = sv[0] * 1e-12 + 1e-300;
    for (int k = 0; k < 3; ++k) {
        double hv[3];
        for (int i = 0; i < 3; ++i)
            hv[i] = Hm[i][0] * Vs[0][k] + Hm[i][1] * Vs[1][k] + Hm[i][2] * Vs[2][k];
        if (sv[k] > eps) {
            double col[3] = {hv[0] / sv[k], hv[1] / sv[k], hv[2] / sv[k]};
            normalize3(col);
            for (int i = 0; i < 3; ++i) U[i][k] = col[i];
        } else if (k == 0) {
            U[0][0] = 1; U[1][0] = 0; U[2][0] = 0;
        } else if (k == 1) {
            double u0[3] = {U[0][0], U[1][0], U[2][0]};
            double ax[3] = {0, 0, 0};
            double a0 = fabs(u0[0]), a1 = fabs(u0[1]), a2 = fabs(u0[2]);
            if (a0 <= a1 && a0 <= a2) ax[0] = 1; else if (a1 <= a2) ax[1] = 1; else ax[2] = 1;
            double col[3]; cross3(u0, ax, col); normalize3(col);
            for (int i = 0; i < 3; ++i) U[i][1] = col[i];
        } else {
            double u0[3] = {U[0][0], U[1][0], U[2][0]};
            double u1[3] = {U[0][1], U[1][1], U[2][1]};
            double col[3]; cross3(u0, u1, col); normalize3(col);
            for (int i = 0; i < 3; ++i) U[i][2] = col[i];
        }
    }

    double detH = Hm[0][0] * (Hm[1][1] * Hm[2][2] - Hm[1][2] * Hm[2][1])
                - Hm[0][1] * (Hm[1][0] * Hm[2][2] - Hm[1][2] * Hm[2][0])
                + Hm[0][2] * (Hm[1][0] * Hm[2][1] - Hm[1][1] * Hm[2][0]);
    double e2 = (detH > 0.0) ? 1.0 : ((detH < 0.0) ? -1.0 : 0.0);

    // R = Vs * diag(1,1,e2) * U^T
    float* o = params + b * 32;
#pragma unroll
    for (int i = 0; i < 3; ++i)
#pragma unroll
        for (int j = 0; j < 3; ++j)
            o[3 * i + j] = (float)(Vs[i][0] * U[j][0] + Vs[i][1] * U[j][1] + e2 * Vs[i][2] * U[j][2]);

    double n = (double)s[16];
    double d0 = 1.24 * cbrt(fmax(n - 15.0, 1e-3)) - 1.8;
    d0 = fmax(d0, 1e-3);
#pragma unroll
    for (int i = 0; i < 3; ++i) { o[9 + i] = (float)mup[i]; o[12 + i] = (float)muq[i]; }
    o[15] = (float)(1.0 / (d0 * d0));
    o[16] = (float)cnt;
}

// ---------------- pass 3: rotate + TM sum ----------------
__global__ __launch_bounds__(256) void k_tm(
    const float* __restrict__ P, const float* __restrict__ Q,
    const void* __restrict__ cmask, const int* __restrict__ flagp,
    const float* __restrict__ params, float* __restrict__ out) {
    int b = blockIdx.x;
    int flag = *flagp;
    const float* pr = params + b * 32;
    float R0 = pr[0], R1 = pr[1], R2 = pr[2];
    float R3 = pr[3], R4 = pr[4], R5 = pr[5];
    float R6 = pr[6], R7 = pr[7], R8 = pr[8];
    float mpx = pr[9], mpy = pr[10], mpz = pr[11];
    float mqx = pr[12], mqy = pr[13], mqz = pr[14];
    float inv = pr[15], cnt = pr[16];

    const float4* Pv = (const float4*)(P + (size_t)b * NFLT);
    const float4* Qv = (const float4*)(Q + (size_t)b * NFLT);
    size_t mbase = (size_t)b * NPTS;

    float acc[1] = {0.0f};
    for (int g = threadIdx.x; g < NGRP; g += 256) {
        float4 p0 = Pv[3 * g + 0], p1 = Pv[3 * g + 1], p2 = Pv[3 * g + 2];
        float4 q0 = Qv[3 * g + 0], q1 = Qv[3 * g + 1], q2 = Qv[3 * g + 2];
        float px[4] = {p0.x, p0.w, p1.z, p2.y};
        float py[4] = {p0.y, p1.x, p1.w, p2.z};
        float pz[4] = {p0.z, p1.y, p2.x, p2.w};
        float qx[4] = {q0.x, q0.w, q1.z, q2.y};
        float qy[4] = {q0.y, q1.x, q1.w, q2.z};
        float qz[4] = {q0.z, q1.y, q2.x, q2.w};
#pragma unroll
        for (int u = 0; u < 4; ++u) {
            float w = load_mask(cmask, flag, mbase + 4 * g + u);
            float pcx = px[u] - mpx, pcy = py[u] - mpy, pcz = pz[u] - mpz;
            float ax = R0 * pcx + R1 * pcy + R2 * pcz;
            float ay = R3 * pcx + R4 * pcy + R5 * pcz;
            float az = R6 * pcx + R7 * pcy + R8 * pcz;
            float dx = ax - (qx[u] - mqx);
            float dy = ay - (qy[u] - mqy);
            float dz = az - (qz[u] - mqz);
            float d2 = dx * dx + dy * dy + dz * dz;
            acc[0] += w / (1.0f + d2 * inv);
        }
    }
    __shared__ float lds[4];
    block_reduce<1>(acc, lds);
    if (threadIdx.x == 0)
        out[b] = (cnt > 0.0f) ? acc[0] / fmaxf(cnt, 1.0f) : 0.0f;
}

// ---------------- launcher ----------------
extern "C" void kernel_launch(void* const* d_in, const int* in_sizes, int n_in,
                              void* d_out, int out_size, void* d_ws, size_t ws_size,
                              hipStream_t stream) {
    const float* P = (const float*)d_in[0];
    const float* Q = (const float*)d_in[1];
    const void* cm = d_in[2];
    const void* rm = d_in[3];
    float* out = (float*)d_out;

    int* flag = (int*)d_ws;
    float* sums = (float*)d_ws + 64;            // BATCH*32 floats
    float* params = sums + BATCH * 32;          // BATCH*32 floats

    k_detect<<<1, 1, 0, stream>>>((const unsigned int*)cm, 256, flag);
    k_sums<<<BATCH, 256, 0, stream>>>(P, Q, cm, rm, flag, sums);
    k_svd<<<(BATCH + 63) / 64, 64, 0, stream>>>(sums, params);
    k_tm<<<BATCH, 256, 0, stream>>>(P, Q, cm, flag, params, out);
}

// Round 2
// 49.683 us; speedup vs baseline: 1.3234x; 1.3234x over previous
//
#include <hip/hip_runtime.h>
#include <math.h>

#define BATCH 512
#define SEQL  2048
#define NPTS  (SEQL*3)        // 6144 points per batch
#define NFLT  (NPTS*3)        // 18432 floats per batch per tensor
#define NGRP  (NPTS/4)        // 1536 groups of 4 points
#define TPB   512             // threads per block for streaming kernels
#define NWAVE (TPB/64)

// ---------------- mask dtype handling ----------------
// flag: 0 = int32 {0,1}, 1 = uint8 {0,1}, 2 = float32
// Per-block detection from the first 256 words of cmask (coalesced, ~free).
__device__ __forceinline__ int detect_flag(const void* cm, int* slds) {
    unsigned int v = ((const unsigned int*)cm)[threadIdx.x & 255];
    bool vi = (v <= 1u);                      // int32 0/1 words
    bool vb = ((v & 0xFEFEFEFEu) == 0u);      // bytes all 0/1
    bool wi = __all(vi);
    bool wb = __all(vb);
    int wid = threadIdx.x >> 6;
    if ((threadIdx.x & 63) == 0) slds[wid] = (wi ? 1 : 0) | (wb ? 2 : 0);
    __syncthreads();
    if (threadIdx.x == 0) {
        int m = 3;
        for (int w = 0; w < (int)(blockDim.x >> 6); ++w) m &= slds[w];
        slds[8] = (m & 1) ? 0 : ((m & 2) ? 1 : 2);
    }
    __syncthreads();
    return slds[8];
}

// load weights for point group g (points 4g..4g+3), vectorized per dtype
__device__ __forceinline__ void load_mask4(const void* m, int flag, size_t g, float* w) {
    if (flag == 1) {
        unsigned int v = ((const unsigned int*)m)[g];
        w[0] = (v & 0x000000FFu) ? 1.f : 0.f;
        w[1] = (v & 0x0000FF00u) ? 1.f : 0.f;
        w[2] = (v & 0x00FF0000u) ? 1.f : 0.f;
        w[3] = (v & 0xFF000000u) ? 1.f : 0.f;
    } else if (flag == 0) {
        int4 v = ((const int4*)m)[g];
        w[0] = v.x ? 1.f : 0.f; w[1] = v.y ? 1.f : 0.f;
        w[2] = v.z ? 1.f : 0.f; w[3] = v.w ? 1.f : 0.f;
    } else {
        float4 v = ((const float4*)m)[g];
        w[0] = v.x != 0.f ? 1.f : 0.f; w[1] = v.y != 0.f ? 1.f : 0.f;
        w[2] = v.z != 0.f ? 1.f : 0.f; w[3] = v.w != 0.f ? 1.f : 0.f;
    }
}

// ---------------- reduction helpers ----------------
template <int K>
__device__ __forceinline__ void block_reduce(float* acc, float* lds) {
#pragma unroll
    for (int k = 0; k < K; ++k) {
#pragma unroll
        for (int off = 32; off > 0; off >>= 1)
            acc[k] += __shfl_down(acc[k], off, 64);
    }
    int lane = threadIdx.x & 63;
    int wid  = threadIdx.x >> 6;
    if (lane == 0) {
#pragma unroll
        for (int k = 0; k < K; ++k) lds[wid * K + k] = acc[k];
    }
    __syncthreads();
    if (threadIdx.x == 0) {
#pragma unroll
        for (int k = 0; k < K; ++k) {
            float s = 0.f;
#pragma unroll
            for (int w = 0; w < NWAVE; ++w) s += lds[w * K + k];
            acc[k] = s;
        }
    }
}

__device__ __forceinline__ void accum_pt(float* a, float w,
                                         float px, float py, float pz,
                                         float qx, float qy, float qz) {
    a[0] += w;
    float wpx = w * px, wpy = w * py, wpz = w * pz;
    a[1] += wpx; a[2] += wpy; a[3] += wpz;
    a[4] += w * qx; a[5] += w * qy; a[6] += w * qz;
    a[7]  += wpx * qx; a[8]  += wpx * qy; a[9]  += wpx * qz;
    a[10] += wpy * qx; a[11] += wpy * qy; a[12] += wpy * qz;
    a[13] += wpz * qx; a[14] += wpz * qy; a[15] += wpz * qz;
}

// ---------------- pass 1: per-batch sums ----------------
// out per batch (stride 32): [0]=cnt [1..3]=sum wP [4..6]=sum wQ
// [7..15]=sum w*P_i*Q_j [16]=residue count
__global__ __launch_bounds__(TPB, 4) void k_sums(
    const float* __restrict__ P, const float* __restrict__ Q,
    const void* __restrict__ cmask, const void* __restrict__ rmask,
    float* __restrict__ sums) {
    int b = blockIdx.x;
    __shared__ int slds[9];
    __shared__ float lds[NWAVE * 17];
    int flag = detect_flag(cmask, slds);

    const float4* Pv = (const float4*)(P + (size_t)b * NFLT);
    const float4* Qv = (const float4*)(Q + (size_t)b * NFLT);
    size_t gbase = (size_t)b * NGRP;

    float acc[17];
#pragma unroll
    for (int k = 0; k < 17; ++k) acc[k] = 0.0f;

    for (int g = threadIdx.x; g < NGRP; g += TPB) {
        float4 p0 = Pv[3 * g + 0], p1 = Pv[3 * g + 1], p2 = Pv[3 * g + 2];
        float4 q0 = Qv[3 * g + 0], q1 = Qv[3 * g + 1], q2 = Qv[3 * g + 2];
        float w[4];
        load_mask4(cmask, flag, gbase + g, w);
        accum_pt(acc, w[0], p0.x, p0.y, p0.z, q0.x, q0.y, q0.z);
        accum_pt(acc, w[1], p0.w, p1.x, p1.y, q0.w, q1.x, q1.y);
        accum_pt(acc, w[2], p1.z, p1.w, p2.x, q1.z, q1.w, q2.x);
        accum_pt(acc, w[3], p2.y, p2.z, p2.w, q2.y, q2.z, q2.w);
    }

    // residue count: SEQL=2048 = 512 groups of 4, one group per thread
    {
        size_t rg = (size_t)b * (SEQL / 4) + threadIdx.x;
        if (flag == 1) {
            unsigned int v = ((const unsigned int*)rmask)[rg];
            acc[16] += (float)__popc(v);   // bytes are 0/1
        } else if (flag == 0) {
            int4 v = ((const int4*)rmask)[rg];
            acc[16] += (v.x ? 1.f : 0.f) + (v.y ? 1.f : 0.f) + (v.z ? 1.f : 0.f) + (v.w ? 1.f : 0.f);
        } else {
            float4 v = ((const float4*)rmask)[rg];
            acc[16] += (v.x != 0.f ? 1.f : 0.f) + (v.y != 0.f ? 1.f : 0.f)
                     + (v.z != 0.f ? 1.f : 0.f) + (v.w != 0.f ? 1.f : 0.f);
        }
    }

    block_reduce<17>(acc, lds);
    if (threadIdx.x == 0) {
#pragma unroll
        for (int k = 0; k < 17; ++k) sums[b * 32 + k] = acc[k];
    }
}

// ---------------- pass 2: per-batch 3x3 Kabsch (double precision) ----------------
__device__ __forceinline__ void normalize3(double* v) {
    double n = sqrt(v[0] * v[0] + v[1] * v[1] + v[2] * v[2]);
    if (n > 1e-300) { v[0] /= n; v[1] /= n; v[2] /= n; }
}
__device__ __forceinline__ void cross3(const double* a, const double* b, double* c) {
    c[0] = a[1] * b[2] - a[2] * b[1];
    c[1] = a[2] * b[0] - a[0] * b[2];
    c[2] = a[0] * b[1] - a[1] * b[0];
}

__global__ void k_svd(const float* __restrict__ sums, float* __restrict__ params) {
    int b = blockIdx.x * blockDim.x + threadIdx.x;
    if (b >= BATCH) return;
    const float* s = sums + b * 32;
    double cnt = (double)s[0];
    double cs = fmax(cnt, 1.0);
    double mup[3], muq[3];
#pragma unroll
    for (int i = 0; i < 3; ++i) { mup[i] = (double)s[1 + i] / cs; muq[i] = (double)s[4 + i] / cs; }
    double Hm[3][3];
#pragma unroll
    for (int i = 0; i < 3; ++i)
#pragma unroll
        for (int j = 0; j < 3; ++j)
            Hm[i][j] = (double)s[7 + 3 * i + j] - cnt * mup[i] * muq[j];

    double A[3][3];
#pragma unroll
    for (int i = 0; i < 3; ++i)
#pragma unroll
        for (int j = 0; j < 3; ++j)
            A[i][j] = Hm[0][i] * Hm[0][j] + Hm[1][i] * Hm[1][j] + Hm[2][i] * Hm[2][j];

    double V[3][3] = {{1, 0, 0}, {0, 1, 0}, {0, 0, 1}};
    const int PP[3] = {0, 0, 1}, QQ[3] = {1, 2, 2};
    for (int sweep = 0; sweep < 10; ++sweep) {
        for (int r = 0; r < 3; ++r) {
            int p = PP[r], q = QQ[r];
            double apq = A[p][q];
            if (fabs(apq) < 1e-280) continue;
            double tau = (A[q][q] - A[p][p]) / (2.0 * apq);
            double t = (tau >= 0.0 ? 1.0 : -1.0) / (fabs(tau) + sqrt(1.0 + tau * tau));
            double c = 1.0 / sqrt(1.0 + t * t);
            double sn = t * c;
            for (int k = 0; k < 3; ++k) {
                double akp = A[k][p], akq = A[k][q];
                A[k][p] = c * akp - sn * akq;
                A[k][q] = sn * akp + c * akq;
            }
            for (int k = 0; k < 3; ++k) {
                double apk = A[p][k], aqk = A[q][k];
                A[p][k] = c * apk - sn * aqk;
                A[q][k] = sn * apk + c * aqk;
            }
            for (int k = 0; k < 3; ++k) {
                double vkp = V[k][p], vkq = V[k][q];
                V[k][p] = c * vkp - sn * vkq;
                V[k][q] = sn * vkp + c * vkq;
            }
        }
    }
    double lam[3] = {A[0][0], A[1][1], A[2][2]};
    int idx[3] = {0, 1, 2};
#pragma unroll
    for (int i = 0; i < 2; ++i)
#pragma unroll
        for (int j = 0; j < 2 - i; ++j)
            if (lam[idx[j]] < lam[idx[j + 1]]) { int t = idx[j]; idx[j] = idx[j + 1]; idx[j + 1] = t; }

    double Vs[3][3];
#pragma unroll
    for (int k = 0; k < 3; ++k)
        for (int i = 0; i < 3; ++i) Vs[i][k] = V[i][idx[k]];
    double sv[3];
#pragma unroll
    for (int k = 0; k < 3; ++k) sv[k] = sqrt(fmax(lam[idx[k]], 0.0));

    double U[3][3];
    double eps = sv[0] * 1e-12 + 1e-300;
    for (int k = 0; k < 3; ++k) {
        double hv[3];
        for (int i = 0; i < 3; ++i)
            hv[i] = Hm[i][0] * Vs[0][k] + Hm[i][1] * Vs[1][k] + Hm[i][2] * Vs[2][k];
        if (sv[k] > eps) {
            double col[3] = {hv[0] / sv[k], hv[1] / sv[k], hv[2] / sv[k]};
            normalize3(col);
            for (int i = 0; i < 3; ++i) U[i][k] = col[i];
        } else if (k == 0) {
            U[0][0] = 1; U[1][0] = 0; U[2][0] = 0;
        } else if (k == 1) {
            double u0[3] = {U[0][0], U[1][0], U[2][0]};
            double ax[3] = {0, 0, 0};
            double a0 = fabs(u0[0]), a1 = fabs(u0[1]), a2 = fabs(u0[2]);
            if (a0 <= a1 && a0 <= a2) ax[0] = 1; else if (a1 <= a2) ax[1] = 1; else ax[2] = 1;
            double col[3]; cross3(u0, ax, col); normalize3(col);
            for (int i = 0; i < 3; ++i) U[i][1] = col[i];
        } else {
            double u0[3] = {U[0][0], U[1][0], U[2][0]};
            double u1[3] = {U[0][1], U[1][1], U[2][1]};
            double col[3]; cross3(u0, u1, col); normalize3(col);
            for (int i = 0; i < 3; ++i) U[i][2] = col[i];
        }
    }

    double detH = Hm[0][0] * (Hm[1][1] * Hm[2][2] - Hm[1][2] * Hm[2][1])
                - Hm[0][1] * (Hm[1][0] * Hm[2][2] - Hm[1][2] * Hm[2][0])
                + Hm[0][2] * (Hm[1][0] * Hm[2][1] - Hm[1][1] * Hm[2][0]);
    double e2 = (detH > 0.0) ? 1.0 : ((detH < 0.0) ? -1.0 : 0.0);

    float* o = params + b * 32;
#pragma unroll
    for (int i = 0; i < 3; ++i)
#pragma unroll
        for (int j = 0; j < 3; ++j)
            o[3 * i + j] = (float)(Vs[i][0] * U[j][0] + Vs[i][1] * U[j][1] + e2 * Vs[i][2] * U[j][2]);

    double n = (double)s[16];
    double d0 = 1.24 * cbrt(fmax(n - 15.0, 1e-3)) - 1.8;
    d0 = fmax(d0, 1e-3);
#pragma unroll
    for (int i = 0; i < 3; ++i) { o[9 + i] = (float)mup[i]; o[12 + i] = (float)muq[i]; }
    o[15] = (float)(1.0 / (d0 * d0));
    o[16] = (float)cnt;
}

// ---------------- pass 3: rotate + TM sum ----------------
__global__ __launch_bounds__(TPB, 4) void k_tm(
    const float* __restrict__ P, const float* __restrict__ Q,
    const void* __restrict__ cmask,
    const float* __restrict__ params, float* __restrict__ out) {
    int b = blockIdx.x;
    __shared__ int slds[9];
    __shared__ float lds[NWAVE];
    int flag = detect_flag(cmask, slds);

    const float* pr = params + b * 32;
    float R0 = pr[0], R1 = pr[1], R2 = pr[2];
    float R3 = pr[3], R4 = pr[4], R5 = pr[5];
    float R6 = pr[6], R7 = pr[7], R8 = pr[8];
    float mpx = pr[9], mpy = pr[10], mpz = pr[11];
    float mqx = pr[12], mqy = pr[13], mqz = pr[14];
    float inv = pr[15], cnt = pr[16];

    const float4* Pv = (const float4*)(P + (size_t)b * NFLT);
    const float4* Qv = (const float4*)(Q + (size_t)b * NFLT);
    size_t gbase = (size_t)b * NGRP;

    float acc[1] = {0.0f};
    for (int g = threadIdx.x; g < NGRP; g += TPB) {
        float4 p0 = Pv[3 * g + 0], p1 = Pv[3 * g + 1], p2 = Pv[3 * g + 2];
        float4 q0 = Qv[3 * g + 0], q1 = Qv[3 * g + 1], q2 = Qv[3 * g + 2];
        float w[4];
        load_mask4(cmask, flag, gbase + g, w);
        float px[4] = {p0.x, p0.w, p1.z, p2.y};
        float py[4] = {p0.y, p1.x, p1.w, p2.z};
        float pz[4] = {p0.z, p1.y, p2.x, p2.w};
        float qx[4] = {q0.x, q0.w, q1.z, q2.y};
        float qy[4] = {q0.y, q1.x, q1.w, q2.z};
        float qz[4] = {q0.z, q1.y, q2.x, q2.w};
#pragma unroll
        for (int u = 0; u < 4; ++u) {
            float pcx = px[u] - mpx, pcy = py[u] - mpy, pcz = pz[u] - mpz;
            float ax = R0 * pcx + R1 * pcy + R2 * pcz;
            float ay = R3 * pcx + R4 * pcy + R5 * pcz;
            float az = R6 * pcx + R7 * pcy + R8 * pcz;
            float dx = ax - (qx[u] - mqx);
            float dy = ay - (qy[u] - mqy);
            float dz = az - (qz[u] - mqz);
            float d2 = dx * dx + dy * dy + dz * dz;
            acc[0] += w[u] / (1.0f + d2 * inv);
        }
    }
    block_reduce<1>(acc, lds);
    if (threadIdx.x == 0)
        out[b] = (cnt > 0.0f) ? acc[0] / fmaxf(cnt, 1.0f) : 0.0f;
}

// ---------------- launcher ----------------
extern "C" void kernel_launch(void* const* d_in, const int* in_sizes, int n_in,
                              void* d_out, int out_size, void* d_ws, size_t ws_size,
                              hipStream_t stream) {
    const float* P = (const float*)d_in[0];
    const float* Q = (const float*)d_in[1];
    const void* cm = d_in[2];
    const void* rm = d_in[3];
    float* out = (float*)d_out;

    float* sums = (float*)d_ws;                 // BATCH*32 floats
    float* params = sums + BATCH * 32;          // BATCH*32 floats

    k_sums<<<BATCH, TPB, 0, stream>>>(P, Q, cm, rm, sums);
    k_svd<<<(BATCH + 63) / 64, 64, 0, stream>>>(sums, params);
    k_tm<<<BATCH, TPB, 0, stream>>>(P, Q, cm, params, out);
}

// Round 3
// 40.187 us; speedup vs baseline: 1.6361x; 1.2363x over previous
//
#include <hip/hip_runtime.h>
#include <math.h>

#define BATCH 512
#define SEQL  2048
#define NPTS  (SEQL*3)        // 6144 points per batch
#define NFLT  (NPTS*3)        // 18432 floats per batch per tensor
#define NGRP  (NPTS/4)        // 1536 groups of 4 points
#define TPB   512
#define NWAVE (TPB/64)

// ---------------- mask dtype handling ----------------
// flag: 0 = int32 {0,1}, 1 = uint8 {0,1}, 2 = float32
__device__ __forceinline__ int detect_flag(const void* cm, int* slds) {
    unsigned int v = ((const unsigned int*)cm)[threadIdx.x & 255];
    bool vi = (v <= 1u);
    bool vb = ((v & 0xFEFEFEFEu) == 0u);
    bool wi = __all(vi);
    bool wb = __all(vb);
    int wid = threadIdx.x >> 6;
    if ((threadIdx.x & 63) == 0) slds[wid] = (wi ? 1 : 0) | (wb ? 2 : 0);
    __syncthreads();
    if (threadIdx.x == 0) {
        int m = 3;
        for (int w = 0; w < (int)(blockDim.x >> 6); ++w) m &= slds[w];
        slds[8] = (m & 1) ? 0 : ((m & 2) ? 1 : 2);
    }
    __syncthreads();
    return slds[8];
}

__device__ __forceinline__ void load_mask4(const void* m, int flag, size_t g, float* w) {
    if (flag == 1) {
        unsigned int v = ((const unsigned int*)m)[g];
        w[0] = (v & 0x000000FFu) ? 1.f : 0.f;
        w[1] = (v & 0x0000FF00u) ? 1.f : 0.f;
        w[2] = (v & 0x00FF0000u) ? 1.f : 0.f;
        w[3] = (v & 0xFF000000u) ? 1.f : 0.f;
    } else if (flag == 0) {
        int4 v = ((const int4*)m)[g];
        w[0] = v.x ? 1.f : 0.f; w[1] = v.y ? 1.f : 0.f;
        w[2] = v.z ? 1.f : 0.f; w[3] = v.w ? 1.f : 0.f;
    } else {
        float4 v = ((const float4*)m)[g];
        w[0] = v.x != 0.f ? 1.f : 0.f; w[1] = v.y != 0.f ? 1.f : 0.f;
        w[2] = v.z != 0.f ? 1.f : 0.f; w[3] = v.w != 0.f ? 1.f : 0.f;
    }
}

// ---------------- reduction ----------------
template <int K>
__device__ __forceinline__ void block_reduce(float* acc, float* lds) {
#pragma unroll
    for (int k = 0; k < K; ++k) {
#pragma unroll
        for (int off = 32; off > 0; off >>= 1)
            acc[k] += __shfl_down(acc[k], off, 64);
    }
    int lane = threadIdx.x & 63;
    int wid  = threadIdx.x >> 6;
    if (lane == 0) {
#pragma unroll
        for (int k = 0; k < K; ++k) lds[wid * K + k] = acc[k];
    }
    __syncthreads();
    if (threadIdx.x == 0) {
#pragma unroll
        for (int k = 0; k < K; ++k) {
            float s = 0.f;
#pragma unroll
            for (int w = 0; w < NWAVE; ++w) s += lds[w * K + k];
            acc[k] = s;
        }
    }
}

__device__ __forceinline__ void accum_pt(float* a, float w,
                                         float px, float py, float pz,
                                         float qx, float qy, float qz) {
    a[0] += w;
    float wpx = w * px, wpy = w * py, wpz = w * pz;
    a[1] += wpx; a[2] += wpy; a[3] += wpz;
    a[4] += w * qx; a[5] += w * qy; a[6] += w * qz;
    a[7]  += wpx * qx; a[8]  += wpx * qy; a[9]  += wpx * qz;
    a[10] += wpy * qx; a[11] += wpy * qy; a[12] += wpy * qz;
    a[13] += wpz * qx; a[14] += wpz * qy; a[15] += wpz * qz;
}

// ---------------- in-thread 3x3 Kabsch (f64), writes 17 params ----------------
__device__ __forceinline__ void normalize3(double* v) {
    double n = sqrt(v[0] * v[0] + v[1] * v[1] + v[2] * v[2]);
    if (n > 1e-300) { v[0] /= n; v[1] /= n; v[2] /= n; }
}
__device__ __forceinline__ void cross3(const double* a, const double* b, double* c) {
    c[0] = a[1] * b[2] - a[2] * b[1];
    c[1] = a[2] * b[0] - a[0] * b[2];
    c[2] = a[0] * b[1] - a[1] * b[0];
}

__device__ void kabsch_params(const float* s, float* o) {
    double cnt = (double)s[0];
    double cs = fmax(cnt, 1.0);
    double mup[3], muq[3];
#pragma unroll
    for (int i = 0; i < 3; ++i) { mup[i] = (double)s[1 + i] / cs; muq[i] = (double)s[4 + i] / cs; }
    double Hm[3][3];
#pragma unroll
    for (int i = 0; i < 3; ++i)
#pragma unroll
        for (int j = 0; j < 3; ++j)
            Hm[i][j] = (double)s[7 + 3 * i + j] - cnt * mup[i] * muq[j];

    double A[3][3];
#pragma unroll
    for (int i = 0; i < 3; ++i)
#pragma unroll
        for (int j = 0; j < 3; ++j)
            A[i][j] = Hm[0][i] * Hm[0][j] + Hm[1][i] * Hm[1][j] + Hm[2][i] * Hm[2][j];

    double V[3][3] = {{1, 0, 0}, {0, 1, 0}, {0, 0, 1}};
    const int PP[3] = {0, 0, 1}, QQ[3] = {1, 2, 2};
    for (int sweep = 0; sweep < 6; ++sweep) {
        for (int r = 0; r < 3; ++r) {
            int p = PP[r], q = QQ[r];
            double apq = A[p][q];
            if (fabs(apq) < 1e-280) continue;
            double tau = (A[q][q] - A[p][p]) / (2.0 * apq);
            double t = (tau >= 0.0 ? 1.0 : -1.0) / (fabs(tau) + sqrt(1.0 + tau * tau));
            double c = 1.0 / sqrt(1.0 + t * t);
            double sn = t * c;
            for (int k = 0; k < 3; ++k) {
                double akp = A[k][p], akq = A[k][q];
                A[k][p] = c * akp - sn * akq;
                A[k][q] = sn * akp + c * akq;
            }
            for (int k = 0; k < 3; ++k) {
                double apk = A[p][k], aqk = A[q][k];
                A[p][k] = c * apk - sn * aqk;
                A[q][k] = sn * apk + c * aqk;
            }
            for (int k = 0; k < 3; ++k) {
                double vkp = V[k][p], vkq = V[k][q];
                V[k][p] = c * vkp - sn * vkq;
                V[k][q] = sn * vkp + c * vkq;
            }
        }
    }
    double lam[3] = {A[0][0], A[1][1], A[2][2]};
    int idx[3] = {0, 1, 2};
#pragma unroll
    for (int i = 0; i < 2; ++i)
#pragma unroll
        for (int j = 0; j < 2 - i; ++j)
            if (lam[idx[j]] < lam[idx[j + 1]]) { int t = idx[j]; idx[j] = idx[j + 1]; idx[j + 1] = t; }

    double Vs[3][3];
#pragma unroll
    for (int k = 0; k < 3; ++k)
        for (int i = 0; i < 3; ++i) Vs[i][k] = V[i][idx[k]];
    double sv[3];
#pragma unroll
    for (int k = 0; k < 3; ++k) sv[k] = sqrt(fmax(lam[idx[k]], 0.0));

    double U[3][3];
    double eps = sv[0] * 1e-12 + 1e-300;
    for (int k = 0; k < 3; ++k) {
        double hv[3];
        for (int i = 0; i < 3; ++i)
            hv[i] = Hm[i][0] * Vs[0][k] + Hm[i][1] * Vs[1][k] + Hm[i][2] * Vs[2][k];
        if (sv[k] > eps) {
            double col[3] = {hv[0] / sv[k], hv[1] / sv[k], hv[2] / sv[k]};
            normalize3(col);
            for (int i = 0; i < 3; ++i) U[i][k] = col[i];
        } else if (k == 0) {
            U[0][0] = 1; U[1][0] = 0; U[2][0] = 0;
        } else if (k == 1) {
            double u0[3] = {U[0][0], U[1][0], U[2][0]};
            double ax[3] = {0, 0, 0};
            double a0 = fabs(u0[0]), a1 = fabs(u0[1]), a2 = fabs(u0[2]);
            if (a0 <= a1 && a0 <= a2) ax[0] = 1; else if (a1 <= a2) ax[1] = 1; else ax[2] = 1;
            double col[3]; cross3(u0, ax, col); normalize3(col);
            for (int i = 0; i < 3; ++i) U[i][1] = col[i];
        } else {
            double u0[3] = {U[0][0], U[1][0], U[2][0]};
            double u1[3] = {U[0][1], U[1][1], U[2][1]};
            double col[3]; cross3(u0, u1, col); normalize3(col);
            for (int i = 0; i < 3; ++i) U[i][2] = col[i];
        }
    }

    double detH = Hm[0][0] * (Hm[1][1] * Hm[2][2] - Hm[1][2] * Hm[2][1])
                - Hm[0][1] * (Hm[1][0] * Hm[2][2] - Hm[1][2] * Hm[2][0])
                + Hm[0][2] * (Hm[1][0] * Hm[2][1] - Hm[1][1] * Hm[2][0]);
    double e2 = (detH > 0.0) ? 1.0 : ((detH < 0.0) ? -1.0 : 0.0);

#pragma unroll
    for (int i = 0; i < 3; ++i)
#pragma unroll
        for (int j = 0; j < 3; ++j)
            o[3 * i + j] = (float)(Vs[i][0] * U[j][0] + Vs[i][1] * U[j][1] + e2 * Vs[i][2] * U[j][2]);

    double n = (double)s[16];
    double d0 = 1.24 * cbrt(fmax(n - 15.0, 1e-3)) - 1.8;
    d0 = fmax(d0, 1e-3);
#pragma unroll
    for (int i = 0; i < 3; ++i) { o[9 + i] = (float)mup[i]; o[12 + i] = (float)muq[i]; }
    o[15] = (float)(1.0 / (d0 * d0));
    o[16] = (float)cnt;
}

// ---------------- fused kernel: sums -> SVD -> TM ----------------
__global__ __launch_bounds__(TPB, 4) void k_fused(
    const float* __restrict__ P, const float* __restrict__ Q,
    const void* __restrict__ cmask, const void* __restrict__ rmask,
    float* __restrict__ out) {
    int b = blockIdx.x;
    __shared__ int slds[9];
    __shared__ float lds[NWAVE * 17];
    __shared__ float prm[17];
    int flag = detect_flag(cmask, slds);

    const float4* Pv = (const float4*)(P + (size_t)b * NFLT);
    const float4* Qv = (const float4*)(Q + (size_t)b * NFLT);
    size_t gbase = (size_t)b * NGRP;

    // ---- phase A: masked sums ----
    float acc[17];
#pragma unroll
    for (int k = 0; k < 17; ++k) acc[k] = 0.0f;

    for (int g = threadIdx.x; g < NGRP; g += TPB) {
        float4 p0 = Pv[3 * g + 0], p1 = Pv[3 * g + 1], p2 = Pv[3 * g + 2];
        float4 q0 = Qv[3 * g + 0], q1 = Qv[3 * g + 1], q2 = Qv[3 * g + 2];
        float w[4];
        load_mask4(cmask, flag, gbase + g, w);
        accum_pt(acc, w[0], p0.x, p0.y, p0.z, q0.x, q0.y, q0.z);
        accum_pt(acc, w[1], p0.w, p1.x, p1.y, q0.w, q1.x, q1.y);
        accum_pt(acc, w[2], p1.z, p1.w, p2.x, q1.z, q1.w, q2.x);
        accum_pt(acc, w[3], p2.y, p2.z, p2.w, q2.y, q2.z, q2.w);
    }

    // residue count: SEQL/4 = 512 groups, one per thread
    {
        size_t rg = (size_t)b * (SEQL / 4) + threadIdx.x;
        if (flag == 1) {
            unsigned int v = ((const unsigned int*)rmask)[rg];
            acc[16] += (float)__popc(v);
        } else if (flag == 0) {
            int4 v = ((const int4*)rmask)[rg];
            acc[16] += (v.x ? 1.f : 0.f) + (v.y ? 1.f : 0.f) + (v.z ? 1.f : 0.f) + (v.w ? 1.f : 0.f);
        } else {
            float4 v = ((const float4*)rmask)[rg];
            acc[16] += (v.x != 0.f ? 1.f : 0.f) + (v.y != 0.f ? 1.f : 0.f)
                     + (v.z != 0.f ? 1.f : 0.f) + (v.w != 0.f ? 1.f : 0.f);
        }
    }

    block_reduce<17>(acc, lds);

    // ---- phase B: thread 0 computes rotation + params ----
    if (threadIdx.x == 0) kabsch_params(acc, prm);
    __syncthreads();

    float R0 = prm[0], R1 = prm[1], R2 = prm[2];
    float R3 = prm[3], R4 = prm[4], R5 = prm[5];
    float R6 = prm[6], R7 = prm[7], R8 = prm[8];
    float mpx = prm[9], mpy = prm[10], mpz = prm[11];
    float mqx = prm[12], mqy = prm[13], mqz = prm[14];
    float inv = prm[15], cnt = prm[16];

    // ---- phase C: rotate + TM sum (re-read, L3-resident) ----
    float acc2[1] = {0.0f};
    for (int g = threadIdx.x; g < NGRP; g += TPB) {
        float4 p0 = Pv[3 * g + 0], p1 = Pv[3 * g + 1], p2 = Pv[3 * g + 2];
        float4 q0 = Qv[3 * g + 0], q1 = Qv[3 * g + 1], q2 = Qv[3 * g + 2];
        float w[4];
        load_mask4(cmask, flag, gbase + g, w);
        float px[4] = {p0.x, p0.w, p1.z, p2.y};
        float py[4] = {p0.y, p1.x, p1.w, p2.z};
        float pz[4] = {p0.z, p1.y, p2.x, p2.w};
        float qx[4] = {q0.x, q0.w, q1.z, q2.y};
        float qy[4] = {q0.y, q1.x, q1.w, q2.z};
        float qz[4] = {q0.z, q1.y, q2.x, q2.w};
#pragma unroll
        for (int u = 0; u < 4; ++u) {
            float pcx = px[u] - mpx, pcy = py[u] - mpy, pcz = pz[u] - mpz;
            float ax = R0 * pcx + R1 * pcy + R2 * pcz;
            float ay = R3 * pcx + R4 * pcy + R5 * pcz;
            float az = R6 * pcx + R7 * pcy + R8 * pcz;
            float dx = ax - (qx[u] - mqx);
            float dy = ay - (qy[u] - mqy);
            float dz = az - (qz[u] - mqz);
            float d2 = dx * dx + dy * dy + dz * dz;
            acc2[0] += w[u] / (1.0f + d2 * inv);
        }
    }
    __syncthreads();   // lds reuse barrier
    block_reduce<1>(acc2, lds);
    if (threadIdx.x == 0)
        out[b] = (cnt > 0.0f) ? acc2[0] / fmaxf(cnt, 1.0f) : 0.0f;
}

// ---------------- launcher ----------------
extern "C" void kernel_launch(void* const* d_in, const int* in_sizes, int n_in,
                              void* d_out, int out_size, void* d_ws, size_t ws_size,
                              hipStream_t stream) {
    const float* P = (const float*)d_in[0];
    const float* Q = (const float*)d_in[1];
    const void* cm = d_in[2];
    const void* rm = d_in[3];
    float* out = (float*)d_out;

    k_fused<<<BATCH, TPB, 0, stream>>>(P, Q, cm, rm, out);
}